// Round 1
// baseline (896.223 us; speedup 1.0000x reference)
//
#include <hip/hip_runtime.h>
#include <hip/hip_bf16.h>
#include <math.h>

// Pipeline:
//  K1 proj:    z[n][f] = (type==1 ? d_sim[n] : m_sim[n]) . (type==1 ? W_d : W_m)[:,f]
//  K2 count:   degree count per dst (atomicAdd int)
//  K3 scan:    exclusive prefix sum -> offsets, cursor (single block)
//  K4 scatter: CSR edge index list by dst
//  K5 attn:    one wave per dst node; online softmax over incoming edges;
//              h = sum alpha*z[src]; out = elu(h)

#define DSIM 256
#define F 64

__global__ void proj_kernel(const float* __restrict__ d_sim,
                            const float* __restrict__ m_sim,
                            const float* __restrict__ W_d,
                            const float* __restrict__ W_m,
                            const int* __restrict__ node_type,
                            float* __restrict__ z, int n) {
    int node = blockIdx.x * 4 + (threadIdx.x >> 6);
    int lane = threadIdx.x & 63;
    if (node >= n) return;
    int t = node_type[node];
    const float* __restrict__ srow = ((t == 1) ? d_sim : m_sim) + (size_t)node * DSIM;
    const float* __restrict__ W    = (t == 1) ? W_d : W_m;
    float acc = 0.f;
    #pragma unroll 4
    for (int k = 0; k < DSIM; k++) {
        acc = fmaf(srow[k], W[k * F + lane], acc);
    }
    z[(size_t)node * F + lane] = acc;
}

__global__ void count_kernel(const int* __restrict__ dst, int* __restrict__ count, int e) {
    int i = blockIdx.x * blockDim.x + threadIdx.x;
    if (i < e) atomicAdd(&count[dst[i]], 1);
}

__global__ void scan_kernel(const int* __restrict__ count, int* __restrict__ offsets,
                            int* __restrict__ cursor, int n) {
    __shared__ int smem[256];
    __shared__ int s_carry;
    if (threadIdx.x == 0) s_carry = 0;
    __syncthreads();
    for (int base = 0; base < n; base += 256) {
        int i = base + (int)threadIdx.x;
        int v = (i < n) ? count[i] : 0;
        smem[threadIdx.x] = v;
        __syncthreads();
        #pragma unroll
        for (int off = 1; off < 256; off <<= 1) {
            int t = (threadIdx.x >= (unsigned)off) ? smem[threadIdx.x - off] : 0;
            __syncthreads();
            smem[threadIdx.x] += t;
            __syncthreads();
        }
        int carry = s_carry;
        int excl = carry + smem[threadIdx.x] - v;
        if (i < n) { offsets[i] = excl; cursor[i] = excl; }
        int total = smem[255];
        __syncthreads();
        if (threadIdx.x == 0) s_carry = carry + total;
        __syncthreads();
    }
    if (threadIdx.x == 0) offsets[n] = s_carry;
}

__global__ void scatter_kernel(const int* __restrict__ dst, int* __restrict__ cursor,
                               int* __restrict__ edge_idx, int e) {
    int i = blockIdx.x * blockDim.x + threadIdx.x;
    if (i < e) {
        int p = atomicAdd(&cursor[dst[i]], 1);
        edge_idx[p] = i;
    }
}

__global__ void attn_kernel(const float* __restrict__ z,
                            const int* __restrict__ src,
                            const int* __restrict__ offsets,
                            const int* __restrict__ edge_idx,
                            float* __restrict__ out, int n) {
    int node = blockIdx.x * 4 + (threadIdx.x >> 6);
    int lane = threadIdx.x & 63;
    if (node >= n) return;
    float zd = z[(size_t)node * F + lane];
    int beg = offsets[node];
    int end = offsets[node + 1];
    float m = -INFINITY, l = 0.f, acc = 0.f;
    for (int i = beg; i < end; i++) {
        int eid = edge_idx[i];
        int s = src[eid];
        float zs = z[(size_t)s * F + lane];
        float p = zs * zd;
        // butterfly reduce across 64 lanes
        #pragma unroll
        for (int off = 32; off > 0; off >>= 1) p += __shfl_xor(p, off, 64);
        float e = (p > 0.f) ? p : 0.2f * p;       // leaky_relu slope 0.2
        float mn = fmaxf(m, e);
        float scale = expf(m - mn);               // first iter: exp(-inf)=0
        float w = expf(e - mn);
        l = l * scale + w;
        acc = acc * scale + w * zs;
        m = mn;
    }
    float h = acc / fmaxf(l, 1e-16f);
    float o = (h > 0.f) ? h : (expf(h) - 1.f);    // elu, alpha=1
    out[(size_t)node * F + lane] = o;
}

extern "C" void kernel_launch(void* const* d_in, const int* in_sizes, int n_in,
                              void* d_out, int out_size, void* d_ws, size_t ws_size,
                              hipStream_t stream) {
    const float* d_sim     = (const float*)d_in[0];
    const float* m_sim     = (const float*)d_in[1];
    const float* W_d       = (const float*)d_in[2];
    const float* W_m       = (const float*)d_in[3];
    const int*   node_type = (const int*)d_in[4];
    const int*   src       = (const int*)d_in[5];
    const int*   dst       = (const int*)d_in[6];
    float* out = (float*)d_out;

    const int N = in_sizes[4];
    const int E = in_sizes[5];

    char* ws = (char*)d_ws;
    float* z        = (float*)ws;                      // N*F floats
    int*   count    = (int*)(ws + (size_t)N * F * 4);  // N
    int*   offsets  = count + N;                       // N+1
    int*   cursor   = offsets + N + 1;                 // N
    int*   edge_idx = cursor + N;                      // E

    hipMemsetAsync(count, 0, (size_t)N * sizeof(int), stream);

    dim3 blk(256);
    proj_kernel<<<dim3((N + 3) / 4), blk, 0, stream>>>(d_sim, m_sim, W_d, W_m, node_type, z, N);
    count_kernel<<<dim3((E + 255) / 256), blk, 0, stream>>>(dst, count, E);
    scan_kernel<<<dim3(1), blk, 0, stream>>>(count, offsets, cursor, N);
    scatter_kernel<<<dim3((E + 255) / 256), blk, 0, stream>>>(dst, cursor, edge_idx, E);
    attn_kernel<<<dim3((N + 3) / 4), blk, 0, stream>>>(z, src, offsets, edge_idx, out, N);
}

// Round 2
// 509.364 us; speedup vs baseline: 1.7595x; 1.7595x over previous
//
#include <hip/hip_runtime.h>
#include <math.h>

// Pipeline:
//  K1 proj:     z[n] = (type?d_sim:m_sim)[n] @ (type?W_d:W_m)   (one wave/node,
//               float4 srow load + shfl broadcast, 4 accumulators)
//  K2 count:    degree per dst (atomicAdd)
//  K3a/b/c scan: multi-block exclusive scan (local -> spine -> add), fills
//               offsets + cursor; offsets[N]=E
//  K4 scatter:  csr_src[pos] = src[e]  (CSR stores src ids directly)
//  K5 attn:     one wave/dst; cooperative 64-wide src load; 4-edge interleaved
//               online softmax; out = elu(sum alpha*z[src])

#define DSIM 256
#define F 64

__global__ void proj_kernel(const float* __restrict__ d_sim,
                            const float* __restrict__ m_sim,
                            const float* __restrict__ W_d,
                            const float* __restrict__ W_m,
                            const int* __restrict__ node_type,
                            float* __restrict__ z, int n) {
    int node = blockIdx.x * 4 + (threadIdx.x >> 6);
    int lane = threadIdx.x & 63;
    if (node >= n) return;
    int t = node_type[node];
    const float* __restrict__ srow = ((t == 1) ? d_sim : m_sim) + (size_t)node * DSIM;
    const float* __restrict__ W    = (((t == 1) ? W_d : W_m)) + lane;
    float4 v = ((const float4*)srow)[lane];   // lane holds k = 4*lane .. 4*lane+3
    float a0 = 0.f, a1 = 0.f, a2 = 0.f, a3 = 0.f;
    #pragma unroll 8
    for (int j = 0; j < 64; j++) {
        float sx = __shfl(v.x, j, 64);
        float sy = __shfl(v.y, j, 64);
        float sz = __shfl(v.z, j, 64);
        float sw = __shfl(v.w, j, 64);
        int k = j * 4;
        a0 = fmaf(sx, W[(k + 0) * F], a0);
        a1 = fmaf(sy, W[(k + 1) * F], a1);
        a2 = fmaf(sz, W[(k + 2) * F], a2);
        a3 = fmaf(sw, W[(k + 3) * F], a3);
    }
    z[(size_t)node * F + lane] = (a0 + a1) + (a2 + a3);
}

__global__ void count_kernel(const int* __restrict__ dst, int* __restrict__ count, int e) {
    int i = blockIdx.x * blockDim.x + threadIdx.x;
    if (i < e) atomicAdd(&count[dst[i]], 1);
}

// local exclusive scan per 256-block; block sums to partials
__global__ void scan_local(const int* __restrict__ count, int* __restrict__ offsets,
                           int* __restrict__ partials, int n) {
    __shared__ int sm[256];
    int i = blockIdx.x * 256 + threadIdx.x;
    int v = (i < n) ? count[i] : 0;
    sm[threadIdx.x] = v;
    __syncthreads();
    #pragma unroll
    for (int off = 1; off < 256; off <<= 1) {
        int t = (threadIdx.x >= (unsigned)off) ? sm[threadIdx.x - off] : 0;
        __syncthreads();
        sm[threadIdx.x] += t;
        __syncthreads();
    }
    if (i < n) offsets[i] = sm[threadIdx.x] - v;   // exclusive within block
    if (threadIdx.x == 255) partials[blockIdx.x] = sm[255];
}

// exclusive scan of block partials (nb <= 256 for N=50000)
__global__ void scan_spine(int* __restrict__ partials, int nb) {
    __shared__ int sm[256];
    int v = ((int)threadIdx.x < nb) ? partials[threadIdx.x] : 0;
    sm[threadIdx.x] = v;
    __syncthreads();
    #pragma unroll
    for (int off = 1; off < 256; off <<= 1) {
        int t = (threadIdx.x >= (unsigned)off) ? sm[threadIdx.x - off] : 0;
        __syncthreads();
        sm[threadIdx.x] += t;
        __syncthreads();
    }
    if ((int)threadIdx.x < nb) partials[threadIdx.x] = sm[threadIdx.x] - v;
}

__global__ void scan_add(int* __restrict__ offsets, const int* __restrict__ partials,
                         int* __restrict__ cursor, int n, int e) {
    int i = blockIdx.x * 256 + threadIdx.x;
    if (i < n) {
        int o = offsets[i] + partials[blockIdx.x];
        offsets[i] = o;
        cursor[i] = o;
    }
    if (i == n) offsets[n] = e;   // total edges
}

__global__ void scatter_kernel(const int* __restrict__ dst, const int* __restrict__ src,
                               int* __restrict__ cursor, int* __restrict__ csr_src, int e) {
    int i = blockIdx.x * blockDim.x + threadIdx.x;
    if (i < e) {
        int p = atomicAdd(&cursor[dst[i]], 1);
        csr_src[p] = src[i];
    }
}

__global__ void attn_kernel(const float* __restrict__ z,
                            const int* __restrict__ offsets,
                            const int* __restrict__ csr_src,
                            float* __restrict__ out, int n) {
    int node = blockIdx.x * 4 + (threadIdx.x >> 6);
    int lane = threadIdx.x & 63;
    if (node >= n) return;
    float zd = z[(size_t)node * F + lane];
    int beg = offsets[node];
    int end = offsets[node + 1];
    float m = -INFINITY, l = 0.f, acc = 0.f;
    for (int base = beg; base < end; base += 64) {
        int cnt = min(64, end - base);
        int s_lane = (base + lane < end) ? csr_src[base + lane] : 0;
        for (int j = 0; j < cnt; j += 4) {
            int s0 = __shfl(s_lane, j + 0, 64);
            int s1 = __shfl(s_lane, j + 1, 64);
            int s2 = __shfl(s_lane, j + 2, 64);
            int s3 = __shfl(s_lane, j + 3, 64);
            // 4 independent gathers in flight (invalid lanes read z[0]: harmless)
            float zs0 = z[(size_t)s0 * F + lane];
            float zs1 = z[(size_t)s1 * F + lane];
            float zs2 = z[(size_t)s2 * F + lane];
            float zs3 = z[(size_t)s3 * F + lane];
            float p0 = zs0 * zd, p1 = zs1 * zd, p2 = zs2 * zd, p3 = zs3 * zd;
            #pragma unroll
            for (int off = 32; off > 0; off >>= 1) {
                p0 += __shfl_xor(p0, off, 64);
                p1 += __shfl_xor(p1, off, 64);
                p2 += __shfl_xor(p2, off, 64);
                p3 += __shfl_xor(p3, off, 64);
            }
            float e0 = (p0 > 0.f) ? p0 : 0.2f * p0;
            float e1 = (p1 > 0.f) ? p1 : 0.2f * p1;
            float e2 = (p2 > 0.f) ? p2 : 0.2f * p2;
            float e3 = (p3 > 0.f) ? p3 : 0.2f * p3;
            if (j + 1 >= cnt) e1 = -INFINITY;
            if (j + 2 >= cnt) e2 = -INFINITY;
            if (j + 3 >= cnt) e3 = -INFINITY;
            float m4 = fmaxf(fmaxf(e0, e1), fmaxf(e2, e3));
            float w0 = __expf(e0 - m4);
            float w1 = __expf(e1 - m4);   // exp(-inf)=0 for tail
            float w2 = __expf(e2 - m4);
            float w3 = __expf(e3 - m4);
            float l4 = (w0 + w1) + (w2 + w3);
            float a4 = fmaf(w3, zs3, fmaf(w2, zs2, fmaf(w1, zs1, w0 * zs0)));
            float mn = fmaxf(m, m4);
            float sc = __expf(m - mn);    // first group: exp(-inf)=0
            float s4 = __expf(m4 - mn);
            l   = fmaf(l, sc, l4 * s4);
            acc = fmaf(acc, sc, a4 * s4);
            m = mn;
        }
    }
    float h = acc / fmaxf(l, 1e-16f);
    out[(size_t)node * F + lane] = (h > 0.f) ? h : (__expf(h) - 1.f);
}

extern "C" void kernel_launch(void* const* d_in, const int* in_sizes, int n_in,
                              void* d_out, int out_size, void* d_ws, size_t ws_size,
                              hipStream_t stream) {
    const float* d_sim     = (const float*)d_in[0];
    const float* m_sim     = (const float*)d_in[1];
    const float* W_d       = (const float*)d_in[2];
    const float* W_m       = (const float*)d_in[3];
    const int*   node_type = (const int*)d_in[4];
    const int*   src       = (const int*)d_in[5];
    const int*   dst       = (const int*)d_in[6];
    float* out = (float*)d_out;

    const int N = in_sizes[4];
    const int E = in_sizes[5];
    const int NB = (N + 255) / 256;   // 196 for N=50000 (spine handles <=256)

    char* ws = (char*)d_ws;
    float* z        = (float*)ws;                        // N*F
    int*   count    = (int*)(ws + (size_t)N * F * 4);    // N
    int*   offsets  = count + N;                         // N+1
    int*   cursor   = offsets + N + 1;                   // N
    int*   partials = cursor + N;                        // NB
    int*   csr_src  = partials + 256;                    // E

    hipMemsetAsync(count, 0, (size_t)N * sizeof(int), stream);

    dim3 blk(256);
    proj_kernel<<<dim3((N + 3) / 4), blk, 0, stream>>>(d_sim, m_sim, W_d, W_m, node_type, z, N);
    count_kernel<<<dim3((E + 255) / 256), blk, 0, stream>>>(dst, count, E);
    scan_local<<<dim3(NB), blk, 0, stream>>>(count, offsets, partials, N);
    scan_spine<<<dim3(1), blk, 0, stream>>>(partials, NB);
    scan_add<<<dim3(NB), blk, 0, stream>>>(offsets, partials, cursor, N, E);
    scatter_kernel<<<dim3((E + 255) / 256), blk, 0, stream>>>(dst, src, cursor, csr_src, E);
    attn_kernel<<<dim3((N + 3) / 4), blk, 0, stream>>>(z, offsets, csr_src, out, N);
}

// Round 3
// 429.227 us; speedup vs baseline: 2.0880x; 1.1867x over previous
//
#include <hip/hip_runtime.h>
#include <math.h>

// Pipeline:
//  K1 proj:   z[n] = (type?d_sim:m_sim)[n] @ (type?W_d:W_m)
//             512-thr blocks, both W's staged in 64KB LDS (two 128-k phases),
//             8 nodes per wave (W LDS-read amortized 8x), srow via uniform loads.
//  K2 count, K3a/b/c scan, K4 scatter: build dst-CSR holding src ids.
//  K5 attn:   one wave/dst, 16-lane groups x 4 f-components; 4 edges/step;
//             group-local online softmax, cross-group merge at end; out=elu().

#define F 64

__global__ __launch_bounds__(512, 1)
void proj_kernel(const float* __restrict__ d_sim, const float* __restrict__ m_sim,
                 const float* __restrict__ W_d, const float* __restrict__ W_m,
                 const int* __restrict__ node_type, float* __restrict__ z, int n) {
    __shared__ float sW[2 * 128 * 64];   // 64KB: [0]=Wd half, [1]=Wm half
    int lane = threadIdx.x & 63;
    int wv = __builtin_amdgcn_readfirstlane((int)(threadIdx.x >> 6));
    int nodeBase = blockIdx.x * 64 + wv * 8;

    float acc[8] = {0.f, 0.f, 0.f, 0.f, 0.f, 0.f, 0.f, 0.f};
    const float* srow[8];
    int isd[8];
    #pragma unroll
    for (int i = 0; i < 8; i++) {
        int node = nodeBase + i;
        if (node >= n) node = n - 1;
        int t = node_type[node];
        isd[i] = (t == 1);
        srow[i] = ((t == 1) ? d_sim : m_sim) + (size_t)node * 256;
    }

    for (int ph = 0; ph < 2; ph++) {
        __syncthreads();
        // stage k in [ph*128, ph*128+128) of both W's: 4096 float4
        for (int i = threadIdx.x; i < 4096; i += 512) {
            float4 v;
            if (i < 2048) v = ((const float4*)W_d)[ph * 2048 + i];
            else          v = ((const float4*)W_m)[ph * 2048 + (i - 2048)];
            ((float4*)sW)[i] = v;
        }
        __syncthreads();
        const float* sWd = sW;
        const float* sWm = sW + 128 * 64;
        int k0 = ph * 128;
        #pragma unroll 8
        for (int k = 0; k < 128; k++) {
            float wd = sWd[k * 64 + lane];
            float wm = sWm[k * 64 + lane];
            #pragma unroll
            for (int i = 0; i < 8; i++) {
                acc[i] = fmaf(srow[i][k0 + k], isd[i] ? wd : wm, acc[i]);
            }
        }
    }
    #pragma unroll
    for (int i = 0; i < 8; i++) {
        int node = nodeBase + i;
        if (node < n) z[(size_t)node * F + lane] = acc[i];
    }
}

__global__ void count_kernel(const int* __restrict__ dst, int* __restrict__ count, int e) {
    int i = blockIdx.x * blockDim.x + threadIdx.x;
    if (i < e) atomicAdd(&count[dst[i]], 1);
}

__global__ void scan_local(const int* __restrict__ count, int* __restrict__ offsets,
                           int* __restrict__ partials, int n) {
    __shared__ int sm[256];
    int i = blockIdx.x * 256 + threadIdx.x;
    int v = (i < n) ? count[i] : 0;
    sm[threadIdx.x] = v;
    __syncthreads();
    #pragma unroll
    for (int off = 1; off < 256; off <<= 1) {
        int t = (threadIdx.x >= (unsigned)off) ? sm[threadIdx.x - off] : 0;
        __syncthreads();
        sm[threadIdx.x] += t;
        __syncthreads();
    }
    if (i < n) offsets[i] = sm[threadIdx.x] - v;
    if (threadIdx.x == 255) partials[blockIdx.x] = sm[255];
}

__global__ void scan_spine(int* __restrict__ partials, int nb) {
    __shared__ int sm[256];
    int v = ((int)threadIdx.x < nb) ? partials[threadIdx.x] : 0;
    sm[threadIdx.x] = v;
    __syncthreads();
    #pragma unroll
    for (int off = 1; off < 256; off <<= 1) {
        int t = (threadIdx.x >= (unsigned)off) ? sm[threadIdx.x - off] : 0;
        __syncthreads();
        sm[threadIdx.x] += t;
        __syncthreads();
    }
    if ((int)threadIdx.x < nb) partials[threadIdx.x] = sm[threadIdx.x] - v;
}

__global__ void scan_add(int* __restrict__ offsets, const int* __restrict__ partials,
                         int* __restrict__ cursor, int n, int e) {
    int i = blockIdx.x * 256 + threadIdx.x;
    if (i < n) {
        int o = offsets[i] + partials[blockIdx.x];
        offsets[i] = o;
        cursor[i] = o;
    }
    if (i == n) offsets[n] = e;
}

__global__ void scatter_kernel(const int* __restrict__ dst, const int* __restrict__ src,
                               int* __restrict__ cursor, int* __restrict__ csr_src, int e) {
    int i = blockIdx.x * blockDim.x + threadIdx.x;
    if (i < e) {
        int p = atomicAdd(&cursor[dst[i]], 1);
        csr_src[p] = src[i];
    }
}

__global__ void attn_kernel(const float* __restrict__ z,
                            const int* __restrict__ offsets,
                            const int* __restrict__ csr_src,
                            float* __restrict__ out, int n) {
    int node = blockIdx.x * 4 + (threadIdx.x >> 6);
    if (node >= n) return;
    int lane = threadIdx.x & 63;
    int g = lane >> 4;    // edge group 0..3
    int r = lane & 15;    // f-quad index
    float4 zd = ((const float4*)(z + (size_t)node * F))[r];
    int beg = offsets[node], end = offsets[node + 1];
    float m = -3.402823466e38f, l = 0.f;
    float4 acc = {0.f, 0.f, 0.f, 0.f};
    for (int base = beg; base < end; base += 64) {
        int cnt = min(64, end - base);
        int s_lane = (base + lane < end) ? csr_src[base + lane] : 0;
        for (int j = 0; j < cnt; j += 4) {
            int idx = j + g;                       // this group's edge slot
            int s = __shfl(s_lane, idx, 64);
            float4 zs = ((const float4*)(z + (size_t)s * F))[r];
            float p = fmaf(zs.x, zd.x, fmaf(zs.y, zd.y, fmaf(zs.z, zd.z, zs.w * zd.w)));
            p += __shfl_xor(p, 1, 64);
            p += __shfl_xor(p, 2, 64);
            p += __shfl_xor(p, 4, 64);
            p += __shfl_xor(p, 8, 64);             // group-wide dot
            float e = (p > 0.f) ? p : 0.2f * p;    // leaky_relu
            if (idx >= cnt) e = -INFINITY;         // invalid slot
            float mn = fmaxf(m, e);
            float sc = __expf(m - mn);             // m >= -3.4e38 => no inf-inf
            float w  = __expf(e - mn);
            l = fmaf(l, sc, w);
            acc.x = fmaf(acc.x, sc, w * zs.x);
            acc.y = fmaf(acc.y, sc, w * zs.y);
            acc.z = fmaf(acc.z, sc, w * zs.z);
            acc.w = fmaf(acc.w, sc, w * zs.w);
            m = mn;
        }
    }
    // merge the 4 groups' (m,l,acc) via xor-16 then xor-32
    #pragma unroll
    for (int off = 16; off <= 32; off <<= 1) {
        float om = __shfl_xor(m, off, 64);
        float ol = __shfl_xor(l, off, 64);
        float4 oa;
        oa.x = __shfl_xor(acc.x, off, 64);
        oa.y = __shfl_xor(acc.y, off, 64);
        oa.z = __shfl_xor(acc.z, off, 64);
        oa.w = __shfl_xor(acc.w, off, 64);
        float mn = fmaxf(m, om);
        float sc = __expf(m - mn);
        float so = __expf(om - mn);
        l = l * sc + ol * so;
        acc.x = acc.x * sc + oa.x * so;
        acc.y = acc.y * sc + oa.y * so;
        acc.z = acc.z * sc + oa.z * so;
        acc.w = acc.w * sc + oa.w * so;
        m = mn;
    }
    float inv = 1.f / fmaxf(l, 1e-16f);
    float4 h;
    h.x = acc.x * inv; h.y = acc.y * inv; h.z = acc.z * inv; h.w = acc.w * inv;
    h.x = (h.x > 0.f) ? h.x : (__expf(h.x) - 1.f);
    h.y = (h.y > 0.f) ? h.y : (__expf(h.y) - 1.f);
    h.z = (h.z > 0.f) ? h.z : (__expf(h.z) - 1.f);
    h.w = (h.w > 0.f) ? h.w : (__expf(h.w) - 1.f);
    if (g == 0) ((float4*)(out + (size_t)node * F))[r] = h;
}

extern "C" void kernel_launch(void* const* d_in, const int* in_sizes, int n_in,
                              void* d_out, int out_size, void* d_ws, size_t ws_size,
                              hipStream_t stream) {
    const float* d_sim     = (const float*)d_in[0];
    const float* m_sim     = (const float*)d_in[1];
    const float* W_d       = (const float*)d_in[2];
    const float* W_m       = (const float*)d_in[3];
    const int*   node_type = (const int*)d_in[4];
    const int*   src       = (const int*)d_in[5];
    const int*   dst       = (const int*)d_in[6];
    float* out = (float*)d_out;

    const int N = in_sizes[4];
    const int E = in_sizes[5];
    const int NB = (N + 255) / 256;   // <=256 assumed by scan_spine

    char* ws = (char*)d_ws;
    float* z        = (float*)ws;                        // N*F
    int*   count    = (int*)(ws + (size_t)N * F * 4);    // N
    int*   offsets  = count + N;                         // N+1
    int*   cursor   = offsets + N + 1;                   // N
    int*   partials = cursor + N;                        // NB (pad to 256)
    int*   csr_src  = partials + 256;                    // E

    hipMemsetAsync(count, 0, (size_t)N * sizeof(int), stream);

    dim3 blk(256);
    proj_kernel<<<dim3((N + 63) / 64), dim3(512), 0, stream>>>(d_sim, m_sim, W_d, W_m,
                                                               node_type, z, N);
    count_kernel<<<dim3((E + 255) / 256), blk, 0, stream>>>(dst, count, E);
    scan_local<<<dim3(NB), blk, 0, stream>>>(count, offsets, partials, N);
    scan_spine<<<dim3(1), blk, 0, stream>>>(partials, NB);
    scan_add<<<dim3(NB), blk, 0, stream>>>(offsets, partials, cursor, N, E);
    scatter_kernel<<<dim3((E + 255) / 256), blk, 0, stream>>>(dst, src, cursor, csr_src, E);
    attn_kernel<<<dim3((N + 3) / 4), blk, 0, stream>>>(z, offsets, csr_src, out, N);
}

// Round 4
// 371.322 us; speedup vs baseline: 2.4136x; 1.1559x over previous
//
#include <hip/hip_runtime.h>
#include <math.h>

// Pipeline:
//  K0 classify: split node ids by type into list0/list1 (wave-aggregated atomics)
//  K1 proj_gemm: per-type register-tiled GEMM  z[list[i]] = A[list[i]] @ W
//               128x64 block tile, K chunks of 64 in LDS, 8x4 register tile.
//  K2 count, K3a/b/c scan, K4 scatter: build dst-CSR holding src ids.
//  K5 attn:   one wave/dst, 16-lane groups x 4 f-components, 4 edges/step,
//             online softmax, cross-group merge; out = elu().

#define F 64
#define TM 128
#define TK 64

__global__ void classify_kernel(const int* __restrict__ node_type, int* __restrict__ tcnt,
                                int* __restrict__ list0, int* __restrict__ list1, int n) {
    int i = blockIdx.x * 256 + threadIdx.x;
    if (i < n) {
        int lane = threadIdx.x & 63;
        int t = node_type[i];
        unsigned long long b1 = __ballot(t == 1);
        unsigned long long ba = __ballot(1);
        unsigned long long mlt = (1ull << lane) - 1ull;
        int r1 = __popcll(b1 & mlt);
        int r0 = __popcll(ba & ~b1 & mlt);
        int base0, base1;
        if (lane == 0) {                     // lane 0 active whenever any lane is
            base1 = atomicAdd(&tcnt[1], __popcll(b1));
            base0 = atomicAdd(&tcnt[0], __popcll(ba & ~b1));
        }
        base0 = __shfl(base0, 0, 64);
        base1 = __shfl(base1, 0, 64);
        if (t == 1) list1[base1 + r1] = i;
        else        list0[base0 + r0] = i;
    }
}

__global__ __launch_bounds__(256, 2)
void proj_gemm(const float* __restrict__ d_sim, const float* __restrict__ m_sim,
               const float* __restrict__ W_d, const float* __restrict__ W_m,
               const int* __restrict__ tcnt, const int* __restrict__ list0,
               const int* __restrict__ list1, float* __restrict__ z) {
    __shared__ float sA[TM][TK + 1];   // pad+1: compute reads hit 4 distinct banks
    __shared__ float sW[TK][F];
    int ty = blockIdx.y;               // 1 -> type1 (d_sim, W_d), 0 -> type0
    int cnt = tcnt[ty];
    int base = blockIdx.x * TM;
    if (base >= cnt) return;
    const int*   list = ty ? list1 : list0;
    const float* A    = ty ? d_sim : m_sim;
    const float* W    = ty ? W_d   : W_m;

    int rg = threadIdx.x >> 4;   // row group 0..15 (8 rows each)
    int cg = threadIdx.x & 15;   // col group 0..15 (4 cols each)

    int srow_node[8];
    #pragma unroll
    for (int j = 0; j < 8; j++) {
        int idx = (int)threadIdx.x + 256 * j;     // 0..2047
        int li = base + (idx >> 4);
        if (li >= cnt) li = cnt - 1;
        srow_node[j] = list[li];
    }

    float acc[8][4] = {};
    for (int kc = 0; kc < 256; kc += TK) {
        __syncthreads();
        #pragma unroll
        for (int j = 0; j < 8; j++) {            // stage A chunk: 128 rows x 64 k
            int idx = (int)threadIdx.x + 256 * j;
            int r = idx >> 4, f4 = idx & 15;
            float4 v = *(const float4*)(A + (size_t)srow_node[j] * 256 + kc + f4 * 4);
            sA[r][f4 * 4 + 0] = v.x;
            sA[r][f4 * 4 + 1] = v.y;
            sA[r][f4 * 4 + 2] = v.z;
            sA[r][f4 * 4 + 3] = v.w;
        }
        #pragma unroll
        for (int j = 0; j < 4; j++) {            // stage W chunk: 64 k x 64 f
            int idx = (int)threadIdx.x + 256 * j;
            int k = idx >> 4, f4 = idx & 15;
            float4 v = *(const float4*)(W + (size_t)(kc + k) * F + f4 * 4);
            *(float4*)&sW[k][f4 * 4] = v;
        }
        __syncthreads();
        #pragma unroll 4
        for (int k = 0; k < TK; k++) {
            float4 wv = *(const float4*)&sW[k][cg * 4];
            float a[8];
            #pragma unroll
            for (int i = 0; i < 8; i++) a[i] = sA[rg * 8 + i][k];
            #pragma unroll
            for (int i = 0; i < 8; i++) {
                acc[i][0] = fmaf(a[i], wv.x, acc[i][0]);
                acc[i][1] = fmaf(a[i], wv.y, acc[i][1]);
                acc[i][2] = fmaf(a[i], wv.z, acc[i][2]);
                acc[i][3] = fmaf(a[i], wv.w, acc[i][3]);
            }
        }
    }
    #pragma unroll
    for (int i = 0; i < 8; i++) {
        int li = base + rg * 8 + i;
        if (li < cnt) {
            int node = list[li];
            float4 v = {acc[i][0], acc[i][1], acc[i][2], acc[i][3]};
            *(float4*)(z + (size_t)node * F + cg * 4) = v;
        }
    }
}

__global__ void count_kernel(const int* __restrict__ dst, int* __restrict__ count, int e) {
    int i = blockIdx.x * blockDim.x + threadIdx.x;
    if (i < e) atomicAdd(&count[dst[i]], 1);
}

__global__ void scan_local(const int* __restrict__ count, int* __restrict__ offsets,
                           int* __restrict__ partials, int n) {
    __shared__ int sm[256];
    int i = blockIdx.x * 256 + threadIdx.x;
    int v = (i < n) ? count[i] : 0;
    sm[threadIdx.x] = v;
    __syncthreads();
    #pragma unroll
    for (int off = 1; off < 256; off <<= 1) {
        int t = (threadIdx.x >= (unsigned)off) ? sm[threadIdx.x - off] : 0;
        __syncthreads();
        sm[threadIdx.x] += t;
        __syncthreads();
    }
    if (i < n) offsets[i] = sm[threadIdx.x] - v;
    if (threadIdx.x == 255) partials[blockIdx.x] = sm[255];
}

__global__ void scan_spine(int* __restrict__ partials, int nb) {
    __shared__ int sm[256];
    int v = ((int)threadIdx.x < nb) ? partials[threadIdx.x] : 0;
    sm[threadIdx.x] = v;
    __syncthreads();
    #pragma unroll
    for (int off = 1; off < 256; off <<= 1) {
        int t = (threadIdx.x >= (unsigned)off) ? sm[threadIdx.x - off] : 0;
        __syncthreads();
        sm[threadIdx.x] += t;
        __syncthreads();
    }
    if ((int)threadIdx.x < nb) partials[threadIdx.x] = sm[threadIdx.x] - v;
}

__global__ void scan_add(int* __restrict__ offsets, const int* __restrict__ partials,
                         int* __restrict__ cursor, int n, int e) {
    int i = blockIdx.x * 256 + threadIdx.x;
    if (i < n) {
        int o = offsets[i] + partials[blockIdx.x];
        offsets[i] = o;
        cursor[i] = o;
    }
    if (i == n) offsets[n] = e;
}

__global__ void scatter_kernel(const int* __restrict__ dst, const int* __restrict__ src,
                               int* __restrict__ cursor, int* __restrict__ csr_src, int e) {
    int i = blockIdx.x * blockDim.x + threadIdx.x;
    if (i < e) {
        int p = atomicAdd(&cursor[dst[i]], 1);
        csr_src[p] = src[i];
    }
}

__global__ void attn_kernel(const float* __restrict__ z,
                            const int* __restrict__ offsets,
                            const int* __restrict__ csr_src,
                            float* __restrict__ out, int n) {
    int node = blockIdx.x * 4 + (threadIdx.x >> 6);
    if (node >= n) return;
    int lane = threadIdx.x & 63;
    int g = lane >> 4;
    int r = lane & 15;
    float4 zd = ((const float4*)(z + (size_t)node * F))[r];
    int beg = offsets[node], end = offsets[node + 1];
    float m = -3.402823466e38f, l = 0.f;
    float4 acc = {0.f, 0.f, 0.f, 0.f};
    for (int base = beg; base < end; base += 64) {
        int cnt = min(64, end - base);
        int s_lane = (base + lane < end) ? csr_src[base + lane] : 0;
        for (int j = 0; j < cnt; j += 4) {
            int idx = j + g;
            int s = __shfl(s_lane, idx, 64);
            float4 zs = ((const float4*)(z + (size_t)s * F))[r];
            float p = fmaf(zs.x, zd.x, fmaf(zs.y, zd.y, fmaf(zs.z, zd.z, zs.w * zd.w)));
            p += __shfl_xor(p, 1, 64);
            p += __shfl_xor(p, 2, 64);
            p += __shfl_xor(p, 4, 64);
            p += __shfl_xor(p, 8, 64);
            float e = (p > 0.f) ? p : 0.2f * p;
            if (idx >= cnt) e = -INFINITY;
            float mn = fmaxf(m, e);
            float sc = __expf(m - mn);
            float w  = __expf(e - mn);
            l = fmaf(l, sc, w);
            acc.x = fmaf(acc.x, sc, w * zs.x);
            acc.y = fmaf(acc.y, sc, w * zs.y);
            acc.z = fmaf(acc.z, sc, w * zs.z);
            acc.w = fmaf(acc.w, sc, w * zs.w);
            m = mn;
        }
    }
    #pragma unroll
    for (int off = 16; off <= 32; off <<= 1) {
        float om = __shfl_xor(m, off, 64);
        float ol = __shfl_xor(l, off, 64);
        float4 oa;
        oa.x = __shfl_xor(acc.x, off, 64);
        oa.y = __shfl_xor(acc.y, off, 64);
        oa.z = __shfl_xor(acc.z, off, 64);
        oa.w = __shfl_xor(acc.w, off, 64);
        float mn = fmaxf(m, om);
        float sc = __expf(m - mn);
        float so = __expf(om - mn);
        l = l * sc + ol * so;
        acc.x = acc.x * sc + oa.x * so;
        acc.y = acc.y * sc + oa.y * so;
        acc.z = acc.z * sc + oa.z * so;
        acc.w = acc.w * sc + oa.w * so;
        m = mn;
    }
    float inv = 1.f / fmaxf(l, 1e-16f);
    float4 h;
    h.x = acc.x * inv; h.y = acc.y * inv; h.z = acc.z * inv; h.w = acc.w * inv;
    h.x = (h.x > 0.f) ? h.x : (__expf(h.x) - 1.f);
    h.y = (h.y > 0.f) ? h.y : (__expf(h.y) - 1.f);
    h.z = (h.z > 0.f) ? h.z : (__expf(h.z) - 1.f);
    h.w = (h.w > 0.f) ? h.w : (__expf(h.w) - 1.f);
    if (g == 0) ((float4*)(out + (size_t)node * F))[r] = h;
}

extern "C" void kernel_launch(void* const* d_in, const int* in_sizes, int n_in,
                              void* d_out, int out_size, void* d_ws, size_t ws_size,
                              hipStream_t stream) {
    const float* d_sim     = (const float*)d_in[0];
    const float* m_sim     = (const float*)d_in[1];
    const float* W_d       = (const float*)d_in[2];
    const float* W_m       = (const float*)d_in[3];
    const int*   node_type = (const int*)d_in[4];
    const int*   src       = (const int*)d_in[5];
    const int*   dst       = (const int*)d_in[6];
    float* out = (float*)d_out;

    const int N = in_sizes[4];
    const int E = in_sizes[5];
    const int NB = (N + 255) / 256;   // <=256 assumed by scan_spine

    char* ws = (char*)d_ws;
    float* z        = (float*)ws;                        // N*F
    int*   count    = (int*)(ws + (size_t)N * F * 4);    // N
    int*   tcnt     = count + N;                         // 2
    int*   offsets  = tcnt + 2;                          // N+1
    int*   cursor   = offsets + N + 1;                   // N
    int*   partials = cursor + N;                        // 256
    int*   csr_src  = partials + 256;                    // E
    // lists alias csr_src: consumed by proj_gemm BEFORE scatter overwrites csr
    int*   list0    = csr_src;                           // N
    int*   list1    = csr_src + N;                       // N

    hipMemsetAsync(count, 0, (size_t)(N + 2) * sizeof(int), stream);

    dim3 blk(256);
    classify_kernel<<<dim3((N + 255) / 256), blk, 0, stream>>>(node_type, tcnt, list0, list1, N);
    proj_gemm<<<dim3((N + TM - 1) / TM, 2), blk, 0, stream>>>(d_sim, m_sim, W_d, W_m,
                                                              tcnt, list0, list1, z);
    count_kernel<<<dim3((E + 255) / 256), blk, 0, stream>>>(dst, count, E);
    scan_local<<<dim3(NB), blk, 0, stream>>>(count, offsets, partials, N);
    scan_spine<<<dim3(1), blk, 0, stream>>>(partials, NB);
    scan_add<<<dim3(NB), blk, 0, stream>>>(offsets, partials, cursor, N, E);
    scatter_kernel<<<dim3((E + 255) / 256), blk, 0, stream>>>(dst, src, cursor, csr_src, E);
    attn_kernel<<<dim3((N + 3) / 4), blk, 0, stream>>>(z, offsets, csr_src, out, N);
}

// Round 5
// 295.714 us; speedup vs baseline: 3.0307x; 1.2557x over previous
//
#include <hip/hip_runtime.h>
#include <math.h>

// Pipeline:
//  K0 classify: split node ids by type into list0/list1 (wave-aggregated atomics)
//  K1 proj_gemm: per-type register-tiled GEMM  z[list[i]] = A[list[i]] @ W
//  B1-B4: two-level counting sort by dst -> offsets[] + csr_src[] (CSR of src ids)
//         (replaces count/scan/scatter: kills the 83MB partial-line write traffic)
//  K5 attn: one wave/dst, 16-lane groups x 4 f-components, 4 edges/step,
//           online softmax, cross-group merge; out = elu().
// Assumes N <= 65536 (src packed into low 16 bits in bucket_data).

#define F 64
#define TM 128
#define TK 64
#define BSH 7                    // bucket = dst >> 7 (128 dsts per bucket)

__global__ void classify_kernel(const int* __restrict__ node_type, int* __restrict__ tcnt,
                                int* __restrict__ list0, int* __restrict__ list1, int n) {
    int i = blockIdx.x * 256 + threadIdx.x;
    if (i < n) {
        int lane = threadIdx.x & 63;
        int t = node_type[i];
        unsigned long long b1 = __ballot(t == 1);
        unsigned long long ba = __ballot(1);
        unsigned long long mlt = (1ull << lane) - 1ull;
        int r1 = __popcll(b1 & mlt);
        int r0 = __popcll(ba & ~b1 & mlt);
        int base0, base1;
        if (lane == 0) {
            base1 = atomicAdd(&tcnt[1], __popcll(b1));
            base0 = atomicAdd(&tcnt[0], __popcll(ba & ~b1));
        }
        base0 = __shfl(base0, 0, 64);
        base1 = __shfl(base1, 0, 64);
        if (t == 1) list1[base1 + r1] = i;
        else        list0[base0 + r0] = i;
    }
}

__global__ __launch_bounds__(256, 2)
void proj_gemm(const float* __restrict__ d_sim, const float* __restrict__ m_sim,
               const float* __restrict__ W_d, const float* __restrict__ W_m,
               const int* __restrict__ tcnt, const int* __restrict__ list0,
               const int* __restrict__ list1, float* __restrict__ z) {
    __shared__ float sA[TM][TK + 1];
    __shared__ float sW[TK][F];
    int ty = blockIdx.y;
    int cnt = tcnt[ty];
    int base = blockIdx.x * TM;
    if (base >= cnt) return;
    const int*   list = ty ? list1 : list0;
    const float* A    = ty ? d_sim : m_sim;
    const float* W    = ty ? W_d   : W_m;

    int rg = threadIdx.x >> 4;
    int cg = threadIdx.x & 15;

    int srow_node[8];
    #pragma unroll
    for (int j = 0; j < 8; j++) {
        int idx = (int)threadIdx.x + 256 * j;
        int li = base + (idx >> 4);
        if (li >= cnt) li = cnt - 1;
        srow_node[j] = list[li];
    }

    float acc[8][4] = {};
    for (int kc = 0; kc < 256; kc += TK) {
        __syncthreads();
        #pragma unroll
        for (int j = 0; j < 8; j++) {
            int idx = (int)threadIdx.x + 256 * j;
            int r = idx >> 4, f4 = idx & 15;
            float4 v = *(const float4*)(A + (size_t)srow_node[j] * 256 + kc + f4 * 4);
            sA[r][f4 * 4 + 0] = v.x;
            sA[r][f4 * 4 + 1] = v.y;
            sA[r][f4 * 4 + 2] = v.z;
            sA[r][f4 * 4 + 3] = v.w;
        }
        #pragma unroll
        for (int j = 0; j < 4; j++) {
            int idx = (int)threadIdx.x + 256 * j;
            int k = idx >> 4, f4 = idx & 15;
            float4 v = *(const float4*)(W + (size_t)(kc + k) * F + f4 * 4);
            *(float4*)&sW[k][f4 * 4] = v;
        }
        __syncthreads();
        #pragma unroll 4
        for (int k = 0; k < TK; k++) {
            float4 wv = *(const float4*)&sW[k][cg * 4];
            float a[8];
            #pragma unroll
            for (int i = 0; i < 8; i++) a[i] = sA[rg * 8 + i][k];
            #pragma unroll
            for (int i = 0; i < 8; i++) {
                acc[i][0] = fmaf(a[i], wv.x, acc[i][0]);
                acc[i][1] = fmaf(a[i], wv.y, acc[i][1]);
                acc[i][2] = fmaf(a[i], wv.z, acc[i][2]);
                acc[i][3] = fmaf(a[i], wv.w, acc[i][3]);
            }
        }
    }
    #pragma unroll
    for (int i = 0; i < 8; i++) {
        int li = base + rg * 8 + i;
        if (li < cnt) {
            int node = list[li];
            float4 v = {acc[i][0], acc[i][1], acc[i][2], acc[i][3]};
            *(float4*)(z + (size_t)node * F + cg * 4) = v;
        }
    }
}

// ---- two-level counting sort by dst ----

__global__ void bucket_hist(const int* __restrict__ dst, int* __restrict__ bucket_count,
                            int e, int nbuk, int chunk) {
    __shared__ int hist[512];
    for (int i = threadIdx.x; i < nbuk; i += 256) hist[i] = 0;
    __syncthreads();
    int beg = blockIdx.x * chunk, end = min(e, beg + chunk);
    for (int i = beg + (int)threadIdx.x; i < end; i += 256)
        atomicAdd(&hist[dst[i] >> BSH], 1);
    __syncthreads();
    for (int i = threadIdx.x; i < nbuk; i += 256)
        if (hist[i]) atomicAdd(&bucket_count[i], hist[i]);
}

__global__ void bucket_scan(const int* __restrict__ bucket_count, int* __restrict__ bucket_base,
                            int* __restrict__ bucket_cursor, int* __restrict__ offsets,
                            int n, int e, int nbuk) {
    __shared__ int sm[512];
    int v = ((int)threadIdx.x < nbuk) ? bucket_count[threadIdx.x] : 0;
    sm[threadIdx.x] = v;
    __syncthreads();
    for (int off = 1; off < 512; off <<= 1) {
        int t = (threadIdx.x >= (unsigned)off) ? sm[threadIdx.x - off] : 0;
        __syncthreads();
        sm[threadIdx.x] += t;
        __syncthreads();
    }
    if ((int)threadIdx.x < nbuk) {
        int b = sm[threadIdx.x] - v;
        bucket_base[threadIdx.x] = b;
        bucket_cursor[threadIdx.x] = b;
    }
    if (threadIdx.x == 0) { bucket_base[nbuk] = e; offsets[n] = e; }
}

__global__ void bucket_scatter(const int* __restrict__ dst, const int* __restrict__ src,
                               int* __restrict__ bucket_cursor, int* __restrict__ bucket_data,
                               int e, int nbuk, int chunk) {
    __shared__ int hist[512], base[512], rk[512];
    for (int i = threadIdx.x; i < nbuk; i += 256) { hist[i] = 0; rk[i] = 0; }
    __syncthreads();
    int beg = blockIdx.x * chunk, end = min(e, beg + chunk);
    for (int i = beg + (int)threadIdx.x; i < end; i += 256)
        atomicAdd(&hist[dst[i] >> BSH], 1);
    __syncthreads();
    for (int i = threadIdx.x; i < nbuk; i += 256)
        base[i] = hist[i] ? atomicAdd(&bucket_cursor[i], hist[i]) : 0;
    __syncthreads();
    for (int i = beg + (int)threadIdx.x; i < end; i += 256) {
        int d = dst[i];
        int b = d >> BSH;
        int r = atomicAdd(&rk[b], 1);
        bucket_data[base[b] + r] = ((d & 127) << 16) | src[i];   // src < 65536
    }
}

__global__ void bucket_csr(const int* __restrict__ bucket_base, const int* __restrict__ bucket_data,
                           int* __restrict__ offsets, int* __restrict__ csr_src, int n) {
    __shared__ int cnt[128], excl[128], cur[128], sm[128];
    int b = blockIdx.x;
    int beg = bucket_base[b], end = bucket_base[b + 1];
    for (int i = threadIdx.x; i < 128; i += 256) { cnt[i] = 0; cur[i] = 0; }
    __syncthreads();
    for (int i = beg + (int)threadIdx.x; i < end; i += 256)
        atomicAdd(&cnt[bucket_data[i] >> 16], 1);
    __syncthreads();
    if (threadIdx.x < 128) sm[threadIdx.x] = cnt[threadIdx.x];
    __syncthreads();
    for (int off = 1; off < 128; off <<= 1) {
        int t = 0;
        if (threadIdx.x < 128 && threadIdx.x >= off) t = sm[threadIdx.x - off];
        __syncthreads();
        if (threadIdx.x < 128) sm[threadIdx.x] += t;
        __syncthreads();
    }
    if (threadIdx.x < 128) {
        excl[threadIdx.x] = sm[threadIdx.x] - cnt[threadIdx.x];
        int d = (b << BSH) + (int)threadIdx.x;
        if (d < n) offsets[d] = beg + excl[threadIdx.x];
    }
    __syncthreads();
    for (int i = beg + (int)threadIdx.x; i < end; i += 256) {
        int v = bucket_data[i];
        int dl = v >> 16;
        int r = atomicAdd(&cur[dl], 1);
        csr_src[beg + excl[dl] + r] = v & 0xFFFF;
    }
}

__global__ void attn_kernel(const float* __restrict__ z,
                            const int* __restrict__ offsets,
                            const int* __restrict__ csr_src,
                            float* __restrict__ out, int n) {
    int node = blockIdx.x * 4 + (threadIdx.x >> 6);
    if (node >= n) return;
    int lane = threadIdx.x & 63;
    int g = lane >> 4;
    int r = lane & 15;
    float4 zd = ((const float4*)(z + (size_t)node * F))[r];
    int beg = offsets[node], end = offsets[node + 1];
    float m = -3.402823466e38f, l = 0.f;
    float4 acc = {0.f, 0.f, 0.f, 0.f};
    for (int base = beg; base < end; base += 64) {
        int cnt = min(64, end - base);
        int s_lane = (base + lane < end) ? csr_src[base + lane] : 0;
        for (int j = 0; j < cnt; j += 4) {
            int idx = j + g;
            int s = __shfl(s_lane, idx, 64);
            float4 zs = ((const float4*)(z + (size_t)s * F))[r];
            float p = fmaf(zs.x, zd.x, fmaf(zs.y, zd.y, fmaf(zs.z, zd.z, zs.w * zd.w)));
            p += __shfl_xor(p, 1, 64);
            p += __shfl_xor(p, 2, 64);
            p += __shfl_xor(p, 4, 64);
            p += __shfl_xor(p, 8, 64);
            float e = (p > 0.f) ? p : 0.2f * p;
            if (idx >= cnt) e = -INFINITY;
            float mn = fmaxf(m, e);
            float sc = __expf(m - mn);
            float w  = __expf(e - mn);
            l = fmaf(l, sc, w);
            acc.x = fmaf(acc.x, sc, w * zs.x);
            acc.y = fmaf(acc.y, sc, w * zs.y);
            acc.z = fmaf(acc.z, sc, w * zs.z);
            acc.w = fmaf(acc.w, sc, w * zs.w);
            m = mn;
        }
    }
    #pragma unroll
    for (int off = 16; off <= 32; off <<= 1) {
        float om = __shfl_xor(m, off, 64);
        float ol = __shfl_xor(l, off, 64);
        float4 oa;
        oa.x = __shfl_xor(acc.x, off, 64);
        oa.y = __shfl_xor(acc.y, off, 64);
        oa.z = __shfl_xor(acc.z, off, 64);
        oa.w = __shfl_xor(acc.w, off, 64);
        float mn = fmaxf(m, om);
        float sc = __expf(m - mn);
        float so = __expf(om - mn);
        l = l * sc + ol * so;
        acc.x = acc.x * sc + oa.x * so;
        acc.y = acc.y * sc + oa.y * so;
        acc.z = acc.z * sc + oa.z * so;
        acc.w = acc.w * sc + oa.w * so;
        m = mn;
    }
    float inv = 1.f / fmaxf(l, 1e-16f);
    float4 h;
    h.x = acc.x * inv; h.y = acc.y * inv; h.z = acc.z * inv; h.w = acc.w * inv;
    h.x = (h.x > 0.f) ? h.x : (__expf(h.x) - 1.f);
    h.y = (h.y > 0.f) ? h.y : (__expf(h.y) - 1.f);
    h.z = (h.z > 0.f) ? h.z : (__expf(h.z) - 1.f);
    h.w = (h.w > 0.f) ? h.w : (__expf(h.w) - 1.f);
    if (g == 0) ((float4*)(out + (size_t)node * F))[r] = h;
}

extern "C" void kernel_launch(void* const* d_in, const int* in_sizes, int n_in,
                              void* d_out, int out_size, void* d_ws, size_t ws_size,
                              hipStream_t stream) {
    const float* d_sim     = (const float*)d_in[0];
    const float* m_sim     = (const float*)d_in[1];
    const float* W_d       = (const float*)d_in[2];
    const float* W_m       = (const float*)d_in[3];
    const int*   node_type = (const int*)d_in[4];
    const int*   src       = (const int*)d_in[5];
    const int*   dst       = (const int*)d_in[6];
    float* out = (float*)d_out;

    const int N = in_sizes[4];
    const int E = in_sizes[5];
    const int NBUK = (N + 127) >> BSH;          // 391 for N=50000 (<=512 assumed)

    char* ws = (char*)d_ws;
    float* z         = (float*)ws;                       // N*F
    int*   tcnt      = (int*)(ws + (size_t)N * F * 4);   // 2
    int*   bcount    = tcnt + 2;                         // NBUK
    int*   bbase     = bcount + 512;                     // NBUK+1
    int*   bcursor   = bbase + 513;                      // NBUK
    int*   offsets   = bcursor + 512;                    // N+1
    int*   list0     = offsets + N + 1;                  // N
    int*   list1     = list0 + N;                        // N
    int*   bdata     = list1 + N;                        // E
    int*   csr_src   = bdata + E;                        // E

    hipMemsetAsync(tcnt, 0, (size_t)(2 + 512) * sizeof(int), stream);

    dim3 blk(256);
    classify_kernel<<<dim3((N + 255) / 256), blk, 0, stream>>>(node_type, tcnt, list0, list1, N);
    proj_gemm<<<dim3((N + TM - 1) / TM, 2), blk, 0, stream>>>(d_sim, m_sim, W_d, W_m,
                                                              tcnt, list0, list1, z);
    int chunk1 = (E + 255) / 256;
    bucket_hist<<<dim3(256), blk, 0, stream>>>(dst, bcount, E, NBUK, chunk1);
    bucket_scan<<<dim3(1), dim3(512), 0, stream>>>(bcount, bbase, bcursor, offsets, N, E, NBUK);
    int chunk3 = (E + 127) / 128;
    bucket_scatter<<<dim3(128), blk, 0, stream>>>(dst, src, bcursor, bdata, E, NBUK, chunk3);
    bucket_csr<<<dim3(NBUK), blk, 0, stream>>>(bbase, bdata, offsets, csr_src, N);
    attn_kernel<<<dim3((N + 3) / 4), blk, 0, stream>>>(z, offsets, csr_src, out, N);
}